// Round 2
// baseline (329.103 us; speedup 1.0000x reference)
//
#include <hip/hip_runtime.h>
#include <hip/hip_bf16.h>

#define B_SZ   8
#define S_LEN  4096
#define D_K    128
#define QB     64      // queries per workgroup
#define KB     64      // keys per step

// LDS strides in shorts (bf16). 136*2=272B == 16 mod 128 -> conflict-free b128 reads.
#define KT_STR 136     // K tile row stride (row = key, 128 d + 8 pad)
#define VT_STR 72      // V^T row stride   (row = d,   64 keys + 8 pad)
#define PT_STR 72      // P scratch row stride (row = q, 64 keys + 8 pad)

typedef short  short8  __attribute__((ext_vector_type(8)));
typedef float  floatx4 __attribute__((ext_vector_type(4)));

#if __has_builtin(__builtin_amdgcn_exp2f)
#define EXP2F(x) __builtin_amdgcn_exp2f(x)
#else
#define EXP2F(x) exp2f(x)
#endif

// f32 -> bf16 (round-to-nearest-even) on raw bits; inputs are finite normals
__device__ __forceinline__ unsigned bfround(float x) {
  unsigned u = __builtin_bit_cast(unsigned, x);
  return (u + 0x7fffu + ((u >> 16) & 1u)) >> 16;
}
// pack two f32 -> two bf16 in one dword (lo = a, hi = b)
__device__ __forceinline__ unsigned bfpack2(float a, float b) {
  return bfround(a) | (bfround(b) << 16);
}

__global__ __launch_bounds__(256, 2)
void attn_fwd(const float* __restrict__ Q, const float* __restrict__ K,
              const float* __restrict__ V, float* __restrict__ O) {
  __shared__ __align__(16) short Klds[KB * KT_STR];    // 17408 B
  __shared__ __align__(16) short Vtlds[D_K * VT_STR];  // 18432 B
  __shared__ __align__(16) short Plds[4 * 16 * PT_STR];//  9216 B

  const int tid  = threadIdx.x;
  const int lane = tid & 63;
  const int w    = tid >> 6;        // wave id 0..3
  const int l15  = lane & 15;
  const int quad = lane >> 4;

  const int bid = blockIdx.x;
  const int b   = bid & 7;
  const int qi  = (S_LEN / QB - 1) - (bid >> 3);  // biggest blocks first
  const int q0  = qi * QB;

  const float CSC = 0.12752041f;    // log2(e) / sqrt(128)

  // ---- preload Q fragments (B-operand: n=l15 -> query, k=quad*8+j -> d) ----
  const int    qg   = q0 + w * 16 + l15;
  const float* qrow = Q + (size_t)(b * S_LEN + qg) * D_K + quad * 8;
  short8 bq[4];
#pragma unroll
  for (int kd = 0; kd < 4; ++kd) {
    float4 f0 = *(const float4*)(qrow + kd * 32);
    float4 f1 = *(const float4*)(qrow + kd * 32 + 4);
    union { short8 s; unsigned u[4]; } t;
    t.u[0] = bfpack2(f0.x, f0.y);
    t.u[1] = bfpack2(f0.z, f0.w);
    t.u[2] = bfpack2(f1.x, f1.y);
    t.u[3] = bfpack2(f1.z, f1.w);
    bq[kd] = t.s;
  }

  floatx4 acc[8];
#pragma unroll
  for (int nc = 0; nc < 8; ++nc) acc[nc] = (floatx4){0.f, 0.f, 0.f, 0.f};
  float m_run = -1e30f, l_run = 0.f;

  // staging decomposition: 256 threads, coalesced float4 reads
  const int d4 = tid & 31;   // float4 column 0..31
  const int kq = tid >> 5;   // row group 0..7

  const int nsteps = q0 / KB + 1;

  for (int s = 0; s < nsteps; ++s) {
    const int kt = s * KB;

    // ---- stage K (row-major bf16) and V (transposed bf16) ----
#pragma unroll
    for (int r2 = 0; r2 < 2; ++r2) {
      const int row = r2 * 32 + kq * 4;   // key row base (4 rows per thread)
      const float* kp = K + (size_t)(b * S_LEN + kt + row) * D_K + d4 * 4;
      const float* vp = V + (size_t)(b * S_LEN + kt + row) * D_K + d4 * 4;
      float4 fk[4], fv[4];
#pragma unroll
      for (int i = 0; i < 4; ++i) {
        fk[i] = *(const float4*)(kp + i * D_K);
        fv[i] = *(const float4*)(vp + i * D_K);
      }
#pragma unroll
      for (int i = 0; i < 4; ++i) {
        uint2 u;
        u.x = bfpack2(fk[i].x, fk[i].y);
        u.y = bfpack2(fk[i].z, fk[i].w);
        *(uint2*)(&Klds[(row + i) * KT_STR + d4 * 4]) = u;
      }
#pragma unroll
      for (int c = 0; c < 4; ++c) {     // 4x4 micro-transpose of V
        float e0 = ((const float*)&fv[0])[c];
        float e1 = ((const float*)&fv[1])[c];
        float e2 = ((const float*)&fv[2])[c];
        float e3 = ((const float*)&fv[3])[c];
        uint2 u;
        u.x = bfpack2(e0, e1);
        u.y = bfpack2(e2, e3);
        *(uint2*)(&Vtlds[(d4 * 4 + c) * VT_STR + row]) = u;
      }
    }
    __syncthreads();

    // ---- S^T = K * Q^T : D[m=key][n=query], C-layout: col=l15=q, row=quad*4+reg=key
    floatx4 st[4];
#pragma unroll
    for (int kf = 0; kf < 4; ++kf) {
      floatx4 c = (floatx4){0.f, 0.f, 0.f, 0.f};
#pragma unroll
      for (int kd = 0; kd < 4; ++kd) {
        short8 a = *(const short8*)(&Klds[(kf * 16 + l15) * KT_STR + kd * 32 + quad * 8]);
        c = __builtin_amdgcn_mfma_f32_16x16x32_bf16(a, bq[kd], c, 0, 0, 0);
      }
      st[kf] = c;
    }

    // ---- causal mask (only the last step can touch keys > q) ----
    if (s == nsteps - 1) {
#pragma unroll
      for (int kf = 0; kf < 4; ++kf)
#pragma unroll
        for (int r = 0; r < 4; ++r) {
          int key = kt + kf * 16 + quad * 4 + r;
          if (key > qg) st[kf][r] = -1e30f;
        }
    }

    // ---- online softmax (per query q=l15; keys split across quads) ----
    float mx = st[0][0];
#pragma unroll
    for (int kf = 0; kf < 4; ++kf)
#pragma unroll
      for (int r = 0; r < 4; ++r) mx = fmaxf(mx, st[kf][r]);
    mx = fmaxf(mx, __shfl_xor(mx, 16, 64));
    mx = fmaxf(mx, __shfl_xor(mx, 32, 64));
    const float m_new = fmaxf(m_run, mx);
    const float alpha = EXP2F((m_run - m_new) * CSC);

    float p[4][4];
    float tsum = 0.f;
#pragma unroll
    for (int kf = 0; kf < 4; ++kf)
#pragma unroll
      for (int r = 0; r < 4; ++r) {
        p[kf][r] = EXP2F((st[kf][r] - m_new) * CSC);
        tsum += p[kf][r];
      }
    tsum += __shfl_xor(tsum, 16, 64);
    tsum += __shfl_xor(tsum, 32, 64);
    l_run = l_run * alpha + tsum;
    m_run = m_new;

    // ---- rescale O accumulator (acc rows are q = quad*4+reg -> fetch alpha by row) ----
#pragma unroll
    for (int r = 0; r < 4; ++r) {
      const float ar = __shfl(alpha, quad * 4 + r, 64);
#pragma unroll
      for (int nc = 0; nc < 8; ++nc) acc[nc][r] *= ar;
    }

    // ---- P: C-layout -> A-layout via per-wave LDS round-trip ----
    short* pw = &Plds[(w * 16 + l15) * PT_STR];
#pragma unroll
    for (int kf = 0; kf < 4; ++kf) {
      uint2 u;
      u.x = bfpack2(p[kf][0], p[kf][1]);
      u.y = bfpack2(p[kf][2], p[kf][3]);
      *(uint2*)(&pw[kf * 16 + quad * 4]) = u;
    }
    __asm__ __volatile__("" ::: "memory");  // keep LDS write->read ordered (same wave, in-order DS)
    short8 pa0 = *(const short8*)(&pw[quad * 8]);
    short8 pa1 = *(const short8*)(&pw[32 + quad * 8]);

    // ---- O += P * V : B-frag from V^T rows (contiguous keys) ----
#pragma unroll
    for (int nc = 0; nc < 8; ++nc) {
      short8 bv0 = *(const short8*)(&Vtlds[(nc * 16 + l15) * VT_STR + quad * 8]);
      acc[nc] = __builtin_amdgcn_mfma_f32_16x16x32_bf16(pa0, bv0, acc[nc], 0, 0, 0);
      short8 bv1 = *(const short8*)(&Vtlds[(nc * 16 + l15) * VT_STR + 32 + quad * 8]);
      acc[nc] = __builtin_amdgcn_mfma_f32_16x16x32_bf16(pa1, bv1, acc[nc], 0, 0, 0);
    }
    __syncthreads();
  }

  // ---- epilogue: O = acc / l ----
#pragma unroll
  for (int r = 0; r < 4; ++r) {
    const float lr  = __shfl(l_run, quad * 4 + r, 64);
    const float inv = 1.0f / lr;
    const int qout  = q0 + w * 16 + quad * 4 + r;
    float* op = O + (size_t)(b * S_LEN + qout) * D_K + l15;
#pragma unroll
    for (int nc = 0; nc < 8; ++nc) op[nc * 16] = acc[nc][r] * inv;
  }
}

extern "C" void kernel_launch(void* const* d_in, const int* in_sizes, int n_in,
                              void* d_out, int out_size, void* d_ws, size_t ws_size,
                              hipStream_t stream) {
  const float* Q = (const float*)d_in[0];
  const float* K = (const float*)d_in[1];
  const float* V = (const float*)d_in[2];
  float* O = (float*)d_out;
  dim3 grid(B_SZ * (S_LEN / QB));   // 512 workgroups
  dim3 block(256);
  attn_fwd<<<grid, block, 0, stream>>>(Q, K, V, O);
}

// Round 3
// 314.768 us; speedup vs baseline: 1.0455x; 1.0455x over previous
//
#include <hip/hip_runtime.h>
#include <hip/hip_bf16.h>

#define B_SZ   8
#define S_LEN  4096
#define D_K    128
#define QB     64      // queries per workgroup
#define KB     64      // keys per step

// LDS strides in shorts (bf16). 272 B / 144 B row strides are both == 16 mod 128
// -> conflict-free b128 writes AND fragment reads.
#define KT_STR 136     // K tile row stride (row = key, 128 d + 8 pad)
#define VT_STR 72      // V^T row stride   (row = d,   64 keys + 8 pad)
#define PT_STR 72      // P scratch row stride (row = q, 64 keys + 8 pad)

typedef short  short8  __attribute__((ext_vector_type(8)));
typedef float  floatx4 __attribute__((ext_vector_type(4)));

#if __has_builtin(__builtin_amdgcn_exp2f)
#define EXP2F(x) __builtin_amdgcn_exp2f(x)
#else
#define EXP2F(x) exp2f(x)
#endif

// f32 -> bf16 (round-to-nearest-even) on raw bits; inputs are finite normals
__device__ __forceinline__ unsigned bfround(float x) {
  unsigned u = __builtin_bit_cast(unsigned, x);
  return (u + 0x7fffu + ((u >> 16) & 1u)) >> 16;
}
__device__ __forceinline__ unsigned bfpack2(float a, float b) {
  return bfround(a) | (bfround(b) << 16);
}

// ======================= pre-pass kernels =======================

// K fp32 -> bf16, layout unchanged [b][s][d]
__global__ __launch_bounds__(256)
void conv_k(const float* __restrict__ K, unsigned short* __restrict__ Kb) {
  const size_t idx = ((size_t)blockIdx.x * 256 + threadIdx.x) * 8;
  float4 f0 = *(const float4*)(K + idx);
  float4 f1 = *(const float4*)(K + idx + 4);
  uint4 u;
  u.x = bfpack2(f0.x, f0.y);
  u.y = bfpack2(f0.z, f0.w);
  u.z = bfpack2(f1.x, f1.y);
  u.w = bfpack2(f1.z, f1.w);
  *(uint4*)(Kb + idx) = u;
}

// V fp32 [b][s][d] -> bf16 transposed Vt [b][d][s]
__global__ __launch_bounds__(256)
void transp_v(const float* __restrict__ V, unsigned short* __restrict__ Vt) {
  __shared__ float tile[64][65];           // +1 pad: conflict-free rows & cols
  const int t   = threadIdx.x;
  const int bid = blockIdx.x;
  const int b   = bid >> 7;
  const int rem = bid & 127;
  const int kt  = (rem >> 1) * 64;
  const int dt  = (rem & 1) * 64;
  {
    const int c  = (t & 15) * 4;
    const int r0 = t >> 4;
#pragma unroll
    for (int rr = 0; rr < 4; ++rr) {
      const int r = r0 + rr * 16;
      float4 f = *(const float4*)(V + (size_t)(b * S_LEN + kt + r) * D_K + dt + c);
      tile[r][c]     = f.x;
      tile[r][c + 1] = f.y;
      tile[r][c + 2] = f.z;
      tile[r][c + 3] = f.w;
    }
  }
  __syncthreads();
  {
    const int d  = t >> 2;
    const int k0 = (t & 3) * 16;
#pragma unroll
    for (int j = 0; j < 16; j += 8) {
      uint4 u;
      u.x = bfpack2(tile[k0 + j + 0][d], tile[k0 + j + 1][d]);
      u.y = bfpack2(tile[k0 + j + 2][d], tile[k0 + j + 3][d]);
      u.z = bfpack2(tile[k0 + j + 4][d], tile[k0 + j + 5][d]);
      u.w = bfpack2(tile[k0 + j + 6][d], tile[k0 + j + 7][d]);
      *(uint4*)(Vt + (size_t)(b * D_K + dt + d) * S_LEN + kt + k0 + j) = u;
    }
  }
}

// ======================= main attention kernel =======================

__global__ __launch_bounds__(256, 2)
void attn_main(const float* __restrict__ Q, const unsigned short* __restrict__ Kb,
               const unsigned short* __restrict__ Vt, float* __restrict__ O) {
  __shared__ __align__(16) short Klds[KB * KT_STR];    // 17408 B
  __shared__ __align__(16) short Vtlds[D_K * VT_STR];  // 18432 B
  __shared__ __align__(16) short Plds[4 * 16 * PT_STR];//  9216 B

  const int tid  = threadIdx.x;
  const int lane = tid & 63;
  const int w    = tid >> 6;
  const int l15  = lane & 15;
  const int quad = lane >> 4;

  // Balanced schedule: bid<256 -> big tile (63-idx), bid>=256 -> small tile idx.
  // CU pairs (bid, bid+256) sum to a uniform 65 steps.
  const int bid  = blockIdx.x;
  const int pair = (bid < 256) ? bid : (bid - 256);
  const int b    = pair & 7;
  const int idx  = pair >> 3;
  const int qi   = (bid < 256) ? (63 - idx) : idx;
  const int q0   = qi * QB;
  const int nsteps = qi + 1;

  const float CSC = 0.12752041f;    // log2(e) / sqrt(128)

  // ---- preload Q fragments (B-operand: n=l15 -> query, k=quad*8+j -> d) ----
  const int    qg   = q0 + w * 16 + l15;
  const float* qrow = Q + (size_t)(b * S_LEN + qg) * D_K + quad * 8;
  short8 bq[4];
#pragma unroll
  for (int kd = 0; kd < 4; ++kd) {
    float4 f0 = *(const float4*)(qrow + kd * 32);
    float4 f1 = *(const float4*)(qrow + kd * 32 + 4);
    union { short8 s; unsigned u[4]; } t;
    t.u[0] = bfpack2(f0.x, f0.y);
    t.u[1] = bfpack2(f0.z, f0.w);
    t.u[2] = bfpack2(f1.x, f1.y);
    t.u[3] = bfpack2(f1.z, f1.w);
    bq[kd] = t.s;
  }

  floatx4 acc[8];
#pragma unroll
  for (int nc = 0; nc < 8; ++nc) acc[nc] = (floatx4){0.f, 0.f, 0.f, 0.f};
  float m_run = -1e30f, l_run = 0.f;

  // staging mapping (pure uint4 copies, no convert, no transpose)
  const int krow = tid >> 4;          // + {0,16,32,48}
  const int kcol = (tid & 15) * 8;    // shorts
  const int vrow = tid >> 3;          // + {0,32,64,96}
  const int vcol = (tid & 7) * 8;     // shorts
  const unsigned short* kbase = Kb + (size_t)(b * S_LEN) * D_K;
  const unsigned short* vbase = Vt + (size_t)(b * D_K) * S_LEN;

  uint4 rk[4], rv[4];
#pragma unroll
  for (int i = 0; i < 4; ++i)
    rk[i] = *(const uint4*)(kbase + (size_t)(krow + i * 16) * D_K + kcol);
#pragma unroll
  for (int i = 0; i < 4; ++i)
    rv[i] = *(const uint4*)(vbase + (size_t)(vrow + i * 32) * S_LEN + vcol);

  for (int s = 0; s < nsteps; ++s) {
    const int kt = s * KB;

    // ---- stage prefetched tile to LDS (conflict-free b128 writes) ----
#pragma unroll
    for (int i = 0; i < 4; ++i)
      *(uint4*)(&Klds[(krow + i * 16) * KT_STR + kcol]) = rk[i];
#pragma unroll
    for (int i = 0; i < 4; ++i)
      *(uint4*)(&Vtlds[(vrow + i * 32) * VT_STR + vcol]) = rv[i];
    __syncthreads();

    // ---- prefetch next tile into registers (overlaps with compute) ----
    if (s + 1 < nsteps) {
      const int kt2 = kt + KB;
#pragma unroll
      for (int i = 0; i < 4; ++i)
        rk[i] = *(const uint4*)(kbase + (size_t)(kt2 + krow + i * 16) * D_K + kcol);
#pragma unroll
      for (int i = 0; i < 4; ++i)
        rv[i] = *(const uint4*)(vbase + (size_t)(vrow + i * 32) * S_LEN + kt2 + vcol);
    }

    // ---- S^T = K * Q^T : C-layout col=l15=q, row=quad*4+reg=key ----
    floatx4 st[4];
#pragma unroll
    for (int kf = 0; kf < 4; ++kf) {
      floatx4 c = (floatx4){0.f, 0.f, 0.f, 0.f};
#pragma unroll
      for (int kd = 0; kd < 4; ++kd) {
        short8 a = *(const short8*)(&Klds[(kf * 16 + l15) * KT_STR + kd * 32 + quad * 8]);
        c = __builtin_amdgcn_mfma_f32_16x16x32_bf16(a, bq[kd], c, 0, 0, 0);
      }
      st[kf] = c;
    }

    // ---- causal mask (only last step can touch keys > q) ----
    if (s == nsteps - 1) {
#pragma unroll
      for (int kf = 0; kf < 4; ++kf)
#pragma unroll
        for (int r = 0; r < 4; ++r) {
          int key = kt + kf * 16 + quad * 4 + r;
          if (key > qg) st[kf][r] = -1e30f;
        }
    }

    // ---- online softmax (per query q=l15; keys split across quads) ----
    float mx = st[0][0];
#pragma unroll
    for (int kf = 0; kf < 4; ++kf)
#pragma unroll
      for (int r = 0; r < 4; ++r) mx = fmaxf(mx, st[kf][r]);
    mx = fmaxf(mx, __shfl_xor(mx, 16, 64));
    mx = fmaxf(mx, __shfl_xor(mx, 32, 64));
    const float m_new = fmaxf(m_run, mx);
    const float alpha = EXP2F((m_run - m_new) * CSC);

    float p[4][4];
    float tsum = 0.f;
#pragma unroll
    for (int kf = 0; kf < 4; ++kf)
#pragma unroll
      for (int r = 0; r < 4; ++r) {
        p[kf][r] = EXP2F((st[kf][r] - m_new) * CSC);
        tsum += p[kf][r];
      }
    tsum += __shfl_xor(tsum, 16, 64);
    tsum += __shfl_xor(tsum, 32, 64);
    l_run = l_run * alpha + tsum;
    m_run = m_new;

    // ---- rescale O accumulator ----
#pragma unroll
    for (int r = 0; r < 4; ++r) {
      const float ar = __shfl(alpha, quad * 4 + r, 64);
#pragma unroll
      for (int nc = 0; nc < 8; ++nc) acc[nc][r] *= ar;
    }

    // ---- P: C-layout -> A-layout via per-wave LDS round-trip ----
    short* pw = &Plds[(w * 16 + l15) * PT_STR];
#pragma unroll
    for (int kf = 0; kf < 4; ++kf) {
      uint2 u;
      u.x = bfpack2(p[kf][0], p[kf][1]);
      u.y = bfpack2(p[kf][2], p[kf][3]);
      *(uint2*)(&pw[kf * 16 + quad * 4]) = u;
    }
    __asm__ __volatile__("" ::: "memory");
    short8 pa0 = *(const short8*)(&pw[quad * 8]);
    short8 pa1 = *(const short8*)(&pw[32 + quad * 8]);

    // ---- O += P * V ----
#pragma unroll
    for (int nc = 0; nc < 8; ++nc) {
      short8 bv0 = *(const short8*)(&Vtlds[(nc * 16 + l15) * VT_STR + quad * 8]);
      acc[nc] = __builtin_amdgcn_mfma_f32_16x16x32_bf16(pa0, bv0, acc[nc], 0, 0, 0);
      short8 bv1 = *(const short8*)(&Vtlds[(nc * 16 + l15) * VT_STR + 32 + quad * 8]);
      acc[nc] = __builtin_amdgcn_mfma_f32_16x16x32_bf16(pa1, bv1, acc[nc], 0, 0, 0);
    }
    __syncthreads();
  }

  // ---- epilogue: O = acc / l ----
#pragma unroll
  for (int r = 0; r < 4; ++r) {
    const float lr  = __shfl(l_run, quad * 4 + r, 64);
    const float inv = 1.0f / lr;
    const int qout  = q0 + w * 16 + quad * 4 + r;
    float* op = O + (size_t)(b * S_LEN + qout) * D_K + l15;
#pragma unroll
    for (int nc = 0; nc < 8; ++nc) op[nc * 16] = acc[nc][r] * inv;
  }
}

// ======================= fallback (R2 kernel, known-good) =======================

__global__ __launch_bounds__(256, 2)
void attn_fwd_fb(const float* __restrict__ Q, const float* __restrict__ K,
                 const float* __restrict__ V, float* __restrict__ O) {
  __shared__ __align__(16) short Klds[KB * KT_STR];
  __shared__ __align__(16) short Vtlds[D_K * VT_STR];
  __shared__ __align__(16) short Plds[4 * 16 * PT_STR];

  const int tid  = threadIdx.x;
  const int lane = tid & 63;
  const int w    = tid >> 6;
  const int l15  = lane & 15;
  const int quad = lane >> 4;

  const int bid = blockIdx.x;
  const int b   = bid & 7;
  const int qi  = (S_LEN / QB - 1) - (bid >> 3);
  const int q0  = qi * QB;

  const float CSC = 0.12752041f;

  const int    qg   = q0 + w * 16 + l15;
  const float* qrow = Q + (size_t)(b * S_LEN + qg) * D_K + quad * 8;
  short8 bq[4];
#pragma unroll
  for (int kd = 0; kd < 4; ++kd) {
    float4 f0 = *(const float4*)(qrow + kd * 32);
    float4 f1 = *(const float4*)(qrow + kd * 32 + 4);
    union { short8 s; unsigned u[4]; } t;
    t.u[0] = bfpack2(f0.x, f0.y);
    t.u[1] = bfpack2(f0.z, f0.w);
    t.u[2] = bfpack2(f1.x, f1.y);
    t.u[3] = bfpack2(f1.z, f1.w);
    bq[kd] = t.s;
  }

  floatx4 acc[8];
#pragma unroll
  for (int nc = 0; nc < 8; ++nc) acc[nc] = (floatx4){0.f, 0.f, 0.f, 0.f};
  float m_run = -1e30f, l_run = 0.f;

  const int d4 = tid & 31;
  const int kq = tid >> 5;
  const int nsteps = q0 / KB + 1;

  for (int s = 0; s < nsteps; ++s) {
    const int kt = s * KB;
#pragma unroll
    for (int r2 = 0; r2 < 2; ++r2) {
      const int row = r2 * 32 + kq * 4;
      const float* kp = K + (size_t)(b * S_LEN + kt + row) * D_K + d4 * 4;
      const float* vp = V + (size_t)(b * S_LEN + kt + row) * D_K + d4 * 4;
      float4 fk[4], fv[4];
#pragma unroll
      for (int i = 0; i < 4; ++i) {
        fk[i] = *(const float4*)(kp + i * D_K);
        fv[i] = *(const float4*)(vp + i * D_K);
      }
#pragma unroll
      for (int i = 0; i < 4; ++i) {
        uint2 u;
        u.x = bfpack2(fk[i].x, fk[i].y);
        u.y = bfpack2(fk[i].z, fk[i].w);
        *(uint2*)(&Klds[(row + i) * KT_STR + d4 * 4]) = u;
      }
#pragma unroll
      for (int c = 0; c < 4; ++c) {
        float e0 = ((const float*)&fv[0])[c];
        float e1 = ((const float*)&fv[1])[c];
        float e2 = ((const float*)&fv[2])[c];
        float e3 = ((const float*)&fv[3])[c];
        uint2 u;
        u.x = bfpack2(e0, e1);
        u.y = bfpack2(e2, e3);
        *(uint2*)(&Vtlds[(d4 * 4 + c) * VT_STR + row]) = u;
      }
    }
    __syncthreads();

    floatx4 st[4];
#pragma unroll
    for (int kf = 0; kf < 4; ++kf) {
      floatx4 c = (floatx4){0.f, 0.f, 0.f, 0.f};
#pragma unroll
      for (int kd = 0; kd < 4; ++kd) {
        short8 a = *(const short8*)(&Klds[(kf * 16 + l15) * KT_STR + kd * 32 + quad * 8]);
        c = __builtin_amdgcn_mfma_f32_16x16x32_bf16(a, bq[kd], c, 0, 0, 0);
      }
      st[kf] = c;
    }

    if (s == nsteps - 1) {
#pragma unroll
      for (int kf = 0; kf < 4; ++kf)
#pragma unroll
        for (int r = 0; r < 4; ++r) {
          int key = kt + kf * 16 + quad * 4 + r;
          if (key > qg) st[kf][r] = -1e30f;
        }
    }

    float mx = st[0][0];
#pragma unroll
    for (int kf = 0; kf < 4; ++kf)
#pragma unroll
      for (int r = 0; r < 4; ++r) mx = fmaxf(mx, st[kf][r]);
    mx = fmaxf(mx, __shfl_xor(mx, 16, 64));
    mx = fmaxf(mx, __shfl_xor(mx, 32, 64));
    const float m_new = fmaxf(m_run, mx);
    const float alpha = EXP2F((m_run - m_new) * CSC);

    float p[4][4];
    float tsum = 0.f;
#pragma unroll
    for (int kf = 0; kf < 4; ++kf)
#pragma unroll
      for (int r = 0; r < 4; ++r) {
        p[kf][r] = EXP2F((st[kf][r] - m_new) * CSC);
        tsum += p[kf][r];
      }
    tsum += __shfl_xor(tsum, 16, 64);
    tsum += __shfl_xor(tsum, 32, 64);
    l_run = l_run * alpha + tsum;
    m_run = m_new;

#pragma unroll
    for (int r = 0; r < 4; ++r) {
      const float ar = __shfl(alpha, quad * 4 + r, 64);
#pragma unroll
      for (int nc = 0; nc < 8; ++nc) acc[nc][r] *= ar;
    }

    short* pw = &Plds[(w * 16 + l15) * PT_STR];
#pragma unroll
    for (int kf = 0; kf < 4; ++kf) {
      uint2 u;
      u.x = bfpack2(p[kf][0], p[kf][1]);
      u.y = bfpack2(p[kf][2], p[kf][3]);
      *(uint2*)(&pw[kf * 16 + quad * 4]) = u;
    }
    __asm__ __volatile__("" ::: "memory");
    short8 pa0 = *(const short8*)(&pw[quad * 8]);
    short8 pa1 = *(const short8*)(&pw[32 + quad * 8]);

#pragma unroll
    for (int nc = 0; nc < 8; ++nc) {
      short8 bv0 = *(const short8*)(&Vtlds[(nc * 16 + l15) * VT_STR + quad * 8]);
      acc[nc] = __builtin_amdgcn_mfma_f32_16x16x32_bf16(pa0, bv0, acc[nc], 0, 0, 0);
      short8 bv1 = *(const short8*)(&Vtlds[(nc * 16 + l15) * VT_STR + 32 + quad * 8]);
      acc[nc] = __builtin_amdgcn_mfma_f32_16x16x32_bf16(pa1, bv1, acc[nc], 0, 0, 0);
    }
    __syncthreads();
  }

#pragma unroll
  for (int r = 0; r < 4; ++r) {
    const float lr  = __shfl(l_run, quad * 4 + r, 64);
    const float inv = 1.0f / lr;
    const int qout  = q0 + w * 16 + quad * 4 + r;
    float* op = O + (size_t)(b * S_LEN + qout) * D_K + l15;
#pragma unroll
    for (int nc = 0; nc < 8; ++nc) op[nc * 16] = acc[nc][r] * inv;
  }
}

extern "C" void kernel_launch(void* const* d_in, const int* in_sizes, int n_in,
                              void* d_out, int out_size, void* d_ws, size_t ws_size,
                              hipStream_t stream) {
  const float* Q = (const float*)d_in[0];
  const float* K = (const float*)d_in[1];
  const float* V = (const float*)d_in[2];
  float* O = (float*)d_out;

  const size_t elems = (size_t)B_SZ * S_LEN * D_K;          // 4.19M
  const size_t need  = elems * 2 /*bf16*/ * 2 /*K + Vt*/;   // 16.78 MB

  if (ws_size >= need) {
    unsigned short* Kb = (unsigned short*)d_ws;
    unsigned short* Vt = Kb + elems;
    conv_k<<<dim3((unsigned)(elems / 8 / 256)), dim3(256), 0, stream>>>(K, Kb);
    transp_v<<<dim3(B_SZ * (S_LEN / 64) * (D_K / 64)), dim3(256), 0, stream>>>(V, Vt);
    attn_main<<<dim3(512), dim3(256), 0, stream>>>(Q, Kb, Vt, O);
  } else {
    attn_fwd_fb<<<dim3(512), dim3(256), 0, stream>>>(Q, K, V, O);
  }
}

// Round 4
// 194.418 us; speedup vs baseline: 1.6928x; 1.6190x over previous
//
#include <hip/hip_runtime.h>
#include <hip/hip_bf16.h>

#define B_SZ   8
#define S_LEN  4096
#define D_K    128
#define KB     64      // keys per step
#define CH     16      // steps per chunk (split-K granularity)
#define NCHUNK 1280    // total chunks (computed: 800 full + 480 remainder)

// LDS strides in shorts. All row strides multiples of 8 shorts (16 B) for b128
// alignment; 272 B / 144 B == 16 mod 128 -> benign bank patterns (R3-verified).
#define KT_STR 136
#define VT_STR 72
#define PT_STR 72

typedef short  short8  __attribute__((ext_vector_type(8)));
typedef float  floatx4 __attribute__((ext_vector_type(4)));

#define EXP2F(x) exp2f(x)

__device__ __forceinline__ unsigned bfround(float x) {
  unsigned u = __builtin_bit_cast(unsigned, x);
  return (u + 0x7fffu + ((u >> 16) & 1u)) >> 16;
}
__device__ __forceinline__ unsigned bfpack2(float a, float b) {
  return bfround(a) | (bfround(b) << 16);
}

// ======================= pre-pass kernels (R3-verified) =======================

__global__ __launch_bounds__(256)
void conv_k(const float* __restrict__ K, unsigned short* __restrict__ Kb) {
  const size_t idx = ((size_t)blockIdx.x * 256 + threadIdx.x) * 8;
  float4 f0 = *(const float4*)(K + idx);
  float4 f1 = *(const float4*)(K + idx + 4);
  uint4 u;
  u.x = bfpack2(f0.x, f0.y);
  u.y = bfpack2(f0.z, f0.w);
  u.z = bfpack2(f1.x, f1.y);
  u.w = bfpack2(f1.z, f1.w);
  *(uint4*)(Kb + idx) = u;
}

__global__ __launch_bounds__(256)
void transp_v(const float* __restrict__ V, unsigned short* __restrict__ Vt) {
  __shared__ float tile[64][65];
  const int t   = threadIdx.x;
  const int bid = blockIdx.x;
  const int b   = bid >> 7;
  const int rem = bid & 127;
  const int kt  = (rem >> 1) * 64;
  const int dt  = (rem & 1) * 64;
  {
    const int c  = (t & 15) * 4;
    const int r0 = t >> 4;
#pragma unroll
    for (int rr = 0; rr < 4; ++rr) {
      const int r = r0 + rr * 16;
      float4 f = *(const float4*)(V + (size_t)(b * S_LEN + kt + r) * D_K + dt + c);
      tile[r][c]     = f.x;
      tile[r][c + 1] = f.y;
      tile[r][c + 2] = f.z;
      tile[r][c + 3] = f.w;
    }
  }
  __syncthreads();
  {
    const int d  = t >> 2;
    const int k0 = (t & 3) * 16;
#pragma unroll
    for (int j = 0; j < 16; j += 8) {
      uint4 u;
      u.x = bfpack2(tile[k0 + j + 0][d], tile[k0 + j + 1][d]);
      u.y = bfpack2(tile[k0 + j + 2][d], tile[k0 + j + 3][d]);
      u.z = bfpack2(tile[k0 + j + 4][d], tile[k0 + j + 5][d]);
      u.w = bfpack2(tile[k0 + j + 6][d], tile[k0 + j + 7][d]);
      *(uint4*)(Vt + (size_t)(b * D_K + dt + d) * S_LEN + kt + k0 + j) = u;
    }
  }
}

__global__ void zero_cnt(int* cnt) { *cnt = 0; }

// ======================= worker kernel =======================
// 128 threads (2 waves); each wave owns 32 queries as two 16-q subtiles that
// SHARE every K A-frag / V B-frag LDS read (halves redundant LDS traffic vs
// the 4-wave R3 design). Chunks of <=16 key-steps pulled from a global atomic
// counter in size-descending order (LPT balance). Writes unnormalized partial
// O + per-query (m,l) for a combine pass.

__global__ __launch_bounds__(128, 2)
void attn_worker(const float* __restrict__ Q, const unsigned short* __restrict__ Kb,
                 const unsigned short* __restrict__ Vt, int* __restrict__ cnt,
                 float* __restrict__ ml, float* __restrict__ pO) {
  __shared__ __align__(16) short Klds[KB * KT_STR];     // 17408 B
  __shared__ __align__(16) short Vtlds[D_K * VT_STR];   // 18432 B
  __shared__ __align__(16) short Plds[2 * 16 * PT_STR]; //  4608 B  (40448 total -> 4 blocks/CU)
  __shared__ int s_chunk;

  const int tid  = threadIdx.x;
  const int lane = tid & 63;
  const int w    = tid >> 6;        // wave 0..1
  const int l15  = lane & 15;
  const int quad = lane >> 4;

  // staging decomposition (128 threads)
  const int kr0 = tid >> 4;         // + i*8,  i=0..7  -> 64 K rows
  const int kc  = (tid & 15) * 8;   // 16 uint4 cols
  const int vr0 = tid >> 3;         // + i*16, i=0..7  -> 128 Vt rows
  const int vc  = (tid & 7) * 8;    // 8 uint4 cols

  const float CSC = 0.12752041f;    // log2(e)/sqrt(128)

  for (;;) {
    if (tid == 0) s_chunk = atomicAdd(cnt, 1);
    __syncthreads();
    const int c = s_chunk;
    if (c >= NCHUNK) break;

    // ---- closed-form decode, chunks enumerated in descending size ----
    int b, qi, j;
    if (c < 800) {                      // full 16-step chunks
      const int r = c >> 3;  b = c & 7;
      if      (r <  4) { qi = 63;               j = r;            }
      else if (r < 52) { qi = 62 - (r-4)/3;     j = (r-4)%3;      }
      else if (r < 84) { qi = 46 - (r-52)/2;    j = (r-52)%2;     }
      else             { qi = 30 - (r-84);      j = 0;            }
    } else {                            // remainder chunks, size 15..1
      const int rc = c - 800;
      const int s  = 15 - (rc >> 5);
      const int t  = rc & 31;
      b  = t & 7;
      qi = s - 1 + 16 * (t >> 3);
      j  = (qi + 1) >> 4;
    }

    const int q0 = qi * 64;
    const int s0 = j * CH;
    const int s1 = min(s0 + CH, qi + 1);

    // ---- Q fragments for 2 subtiles (B-operand: n=l15=query, k=quad*8+j=d) ----
    short8 bq[2][4];
    int qg[2];
#pragma unroll
    for (int sub = 0; sub < 2; ++sub) {
      qg[sub] = q0 + w * 32 + sub * 16 + l15;
      const float* qrow = Q + (size_t)(b * S_LEN + qg[sub]) * D_K + quad * 8;
#pragma unroll
      for (int kd = 0; kd < 4; ++kd) {
        float4 f0 = *(const float4*)(qrow + kd * 32);
        float4 f1 = *(const float4*)(qrow + kd * 32 + 4);
        union { short8 s; unsigned u[4]; } t;
        t.u[0] = bfpack2(f0.x, f0.y);
        t.u[1] = bfpack2(f0.z, f0.w);
        t.u[2] = bfpack2(f1.x, f1.y);
        t.u[3] = bfpack2(f1.z, f1.w);
        bq[sub][kd] = t.s;
      }
    }

    floatx4 acc[2][8];
#pragma unroll
    for (int sub = 0; sub < 2; ++sub)
#pragma unroll
      for (int nc = 0; nc < 8; ++nc) acc[sub][nc] = (floatx4){0.f, 0.f, 0.f, 0.f};
    float m_run[2] = {-1e30f, -1e30f}, l_run[2] = {0.f, 0.f};

    const unsigned short* kbase = Kb + (size_t)(b * S_LEN) * D_K;
    const unsigned short* vbase = Vt + (size_t)(b * D_K) * S_LEN;

    for (int s = s0; s < s1; ++s) {
      const int kt = s * KB;

      // ---- stage K + V^T tiles (pure uint4 copies) ----
#pragma unroll
      for (int i = 0; i < 8; ++i) {
        uint4 u = *(const uint4*)(kbase + (size_t)(kt + kr0 + i * 8) * D_K + kc);
        *(uint4*)(&Klds[(kr0 + i * 8) * KT_STR + kc]) = u;
      }
#pragma unroll
      for (int i = 0; i < 8; ++i) {
        uint4 u = *(const uint4*)(vbase + (size_t)(vr0 + i * 16) * S_LEN + kt + vc);
        *(uint4*)(&Vtlds[(vr0 + i * 16) * VT_STR + vc]) = u;
      }
      __syncthreads();

      // ---- S^T = K*Q^T for both subtiles; each A-frag read used twice ----
      floatx4 st[2][4];
#pragma unroll
      for (int kf = 0; kf < 4; ++kf) {
        floatx4 c0 = (floatx4){0.f, 0.f, 0.f, 0.f};
        floatx4 c1 = (floatx4){0.f, 0.f, 0.f, 0.f};
#pragma unroll
        for (int kd = 0; kd < 4; ++kd) {
          short8 a = *(const short8*)(&Klds[(kf * 16 + l15) * KT_STR + kd * 32 + quad * 8]);
          c0 = __builtin_amdgcn_mfma_f32_16x16x32_bf16(a, bq[0][kd], c0, 0, 0, 0);
          c1 = __builtin_amdgcn_mfma_f32_16x16x32_bf16(a, bq[1][kd], c1, 0, 0, 0);
        }
        st[0][kf] = c0;
        st[1][kf] = c1;
      }

      // ---- causal mask (diagonal step only) ----
      if (s == qi) {
#pragma unroll
        for (int sub = 0; sub < 2; ++sub)
#pragma unroll
          for (int kf = 0; kf < 4; ++kf)
#pragma unroll
            for (int r = 0; r < 4; ++r) {
              int key = kt + kf * 16 + quad * 4 + r;
              if (key > qg[sub]) st[sub][kf][r] = -1e30f;
            }
      }

      // ---- online softmax + P roundtrip + rescale, per subtile ----
      short8 pa[2][2];
#pragma unroll
      for (int sub = 0; sub < 2; ++sub) {
        float mx = st[sub][0][0];
#pragma unroll
        for (int kf = 0; kf < 4; ++kf)
#pragma unroll
          for (int r = 0; r < 4; ++r) mx = fmaxf(mx, st[sub][kf][r]);
        mx = fmaxf(mx, __shfl_xor(mx, 16, 64));
        mx = fmaxf(mx, __shfl_xor(mx, 32, 64));
        const float m_new = fmaxf(m_run[sub], mx);
        const float alpha = EXP2F((m_run[sub] - m_new) * CSC);

        float p[4][4];
        float tsum = 0.f;
#pragma unroll
        for (int kf = 0; kf < 4; ++kf)
#pragma unroll
          for (int r = 0; r < 4; ++r) {
            p[kf][r] = EXP2F((st[sub][kf][r] - m_new) * CSC);
            tsum += p[kf][r];
          }
        tsum += __shfl_xor(tsum, 16, 64);
        tsum += __shfl_xor(tsum, 32, 64);
        l_run[sub] = l_run[sub] * alpha + tsum;
        m_run[sub] = m_new;

#pragma unroll
        for (int r = 0; r < 4; ++r) {
          const float ar = __shfl(alpha, quad * 4 + r, 64);
#pragma unroll
          for (int nc = 0; nc < 8; ++nc) acc[sub][nc][r] *= ar;
        }

        // P: C-layout -> A-layout; both subtiles reuse the same wave-private rows
        // (in-order LDS per wave makes write->read->write safe)
        short* pw = &Plds[(w * 16 + l15) * PT_STR];
#pragma unroll
        for (int kf = 0; kf < 4; ++kf) {
          uint2 u;
          u.x = bfpack2(p[kf][0], p[kf][1]);
          u.y = bfpack2(p[kf][2], p[kf][3]);
          *(uint2*)(&pw[kf * 16 + quad * 4]) = u;
        }
        __asm__ __volatile__("" ::: "memory");
        pa[sub][0] = *(const short8*)(&pw[quad * 8]);
        pa[sub][1] = *(const short8*)(&pw[32 + quad * 8]);
        __asm__ __volatile__("" ::: "memory");
      }

      // ---- O += P*V ; each B-frag read used by both subtiles ----
#pragma unroll
      for (int nc = 0; nc < 8; ++nc) {
        short8 bv0 = *(const short8*)(&Vtlds[(nc * 16 + l15) * VT_STR + quad * 8]);
        short8 bv1 = *(const short8*)(&Vtlds[(nc * 16 + l15) * VT_STR + 32 + quad * 8]);
        acc[0][nc] = __builtin_amdgcn_mfma_f32_16x16x32_bf16(pa[0][0], bv0, acc[0][nc], 0, 0, 0);
        acc[0][nc] = __builtin_amdgcn_mfma_f32_16x16x32_bf16(pa[0][1], bv1, acc[0][nc], 0, 0, 0);
        acc[1][nc] = __builtin_amdgcn_mfma_f32_16x16x32_bf16(pa[1][0], bv0, acc[1][nc], 0, 0, 0);
        acc[1][nc] = __builtin_amdgcn_mfma_f32_16x16x32_bf16(pa[1][1], bv1, acc[1][nc], 0, 0, 0);
      }
      __syncthreads();
    }

    // ---- partial epilogue: unnormalized O + (m,l) ----
    const int slot = ((b << 6) | qi) * 4 + j;
    float* po = pO + (size_t)slot * 8192;
#pragma unroll
    for (int sub = 0; sub < 2; ++sub) {
#pragma unroll
      for (int r = 0; r < 4; ++r) {
        const int qrow = w * 32 + sub * 16 + quad * 4 + r;
        float* op = po + qrow * D_K + l15;
#pragma unroll
        for (int nc = 0; nc < 8; ++nc) op[nc * 16] = acc[sub][nc][r];
      }
      if (quad == 0) {
        const int qrow = w * 32 + sub * 16 + l15;
        ml[(size_t)slot * 128 + qrow * 2]     = m_run[sub];
        ml[(size_t)slot * 128 + qrow * 2 + 1] = l_run[sub];
      }
    }
  }
}

// ======================= combine kernel =======================

__global__ __launch_bounds__(256)
void attn_combine(const float* __restrict__ ml, const float* __restrict__ pO,
                  float* __restrict__ O) {
  const int t   = blockIdx.x;        // tile = b*64 + qi
  const int b   = t >> 6;
  const int qi  = t & 63;
  const int ncb = ((qi + 1) + 15) >> 4;   // chunks for this tile (1..4)
  const float CSC = 0.12752041f;

  const int tid = threadIdx.x;
  const int q   = tid >> 2;          // 0..63
  const int dp  = (tid & 3) * 32;    // d-span of 32 floats

  float m[4], l[4];
  float M = -1e30f;
  for (int jj = 0; jj < ncb; ++jj) {
    const int slot = t * 4 + jj;
    m[jj] = ml[(size_t)slot * 128 + q * 2];
    l[jj] = ml[(size_t)slot * 128 + q * 2 + 1];
    M = fmaxf(M, m[jj]);
  }
  float wgt[4], L = 0.f;
  for (int jj = 0; jj < ncb; ++jj) {
    wgt[jj] = EXP2F((m[jj] - M) * CSC);
    L += wgt[jj] * l[jj];
  }
  const float inv = 1.0f / L;

  float4 out[8];
#pragma unroll
  for (int v = 0; v < 8; ++v) out[v] = make_float4(0.f, 0.f, 0.f, 0.f);
  for (int jj = 0; jj < ncb; ++jj) {
    const float* src = pO + (size_t)(t * 4 + jj) * 8192 + q * D_K + dp;
    const float wj = wgt[jj];
#pragma unroll
    for (int v = 0; v < 8; ++v) {
      float4 f = *(const float4*)(src + v * 4);
      out[v].x += wj * f.x;  out[v].y += wj * f.y;
      out[v].z += wj * f.z;  out[v].w += wj * f.w;
    }
  }
  float* dst = O + (size_t)(b * S_LEN + qi * 64 + q) * D_K + dp;
#pragma unroll
  for (int v = 0; v < 8; ++v) {
    float4 f = make_float4(out[v].x * inv, out[v].y * inv, out[v].z * inv, out[v].w * inv);
    *(float4*)(dst + v * 4) = f;
  }
}

// ======================= fallback (R2 kernel, known-good) =======================

__global__ __launch_bounds__(256, 2)
void attn_fwd_fb(const float* __restrict__ Q, const float* __restrict__ K,
                 const float* __restrict__ V, float* __restrict__ O) {
  __shared__ __align__(16) short Klds[KB * KT_STR];
  __shared__ __align__(16) short Vtlds[D_K * VT_STR];
  __shared__ __align__(16) short Plds[4 * 16 * PT_STR];

  const int tid  = threadIdx.x;
  const int lane = tid & 63;
  const int w    = tid >> 6;
  const int l15  = lane & 15;
  const int quad = lane >> 4;

  const int bid = blockIdx.x;
  const int b   = bid & 7;
  const int qi  = 63 - (bid >> 3);
  const int q0  = qi * 64;

  const float CSC = 0.12752041f;

  const int    qg   = q0 + w * 16 + l15;
  const float* qrow = Q + (size_t)(b * S_LEN + qg) * D_K + quad * 8;
  short8 bq[4];
#pragma unroll
  for (int kd = 0; kd < 4; ++kd) {
    float4 f0 = *(const float4*)(qrow + kd * 32);
    float4 f1 = *(const float4*)(qrow + kd * 32 + 4);
    union { short8 s; unsigned u[4]; } t;
    t.u[0] = bfpack2(f0.x, f0.y);
    t.u[1] = bfpack2(f0.z, f0.w);
    t.u[2] = bfpack2(f1.x, f1.y);
    t.u[3] = bfpack2(f1.z, f1.w);
    bq[kd] = t.s;
  }

  floatx4 acc[8];
#pragma unroll
  for (int nc = 0; nc < 8; ++nc) acc[nc] = (floatx4){0.f, 0.f, 0.f, 0.f};
  float m_run = -1e30f, l_run = 0.f;

  const int d4 = tid & 31;
  const int kq = tid >> 5;
  const int nsteps = qi + 1;

  for (int s = 0; s < nsteps; ++s) {
    const int kt = s * KB;
#pragma unroll
    for (int r2 = 0; r2 < 2; ++r2) {
      const int row = r2 * 32 + kq * 4;
      const float* kp = K + (size_t)(b * S_LEN + kt + row) * D_K + d4 * 4;
      const float* vp = V + (size_t)(b * S_LEN + kt + row) * D_K + d4 * 4;
      float4 fk[4], fv[4];
#pragma unroll
      for (int i = 0; i < 4; ++i) {
        fk[i] = *(const float4*)(kp + i * D_K);
        fv[i] = *(const float4*)(vp + i * D_K);
      }
#pragma unroll
      for (int i = 0; i < 4; ++i) {
        uint2 u;
        u.x = bfpack2(fk[i].x, fk[i].y);
        u.y = bfpack2(fk[i].z, fk[i].w);
        *(uint2*)(&Klds[(row + i) * KT_STR + d4 * 4]) = u;
      }
#pragma unroll
      for (int c = 0; c < 4; ++c) {
        float e0 = ((const float*)&fv[0])[c];
        float e1 = ((const float*)&fv[1])[c];
        float e2 = ((const float*)&fv[2])[c];
        float e3 = ((const float*)&fv[3])[c];
        uint2 u;
        u.x = bfpack2(e0, e1);
        u.y = bfpack2(e2, e3);
        *(uint2*)(&Vtlds[(d4 * 4 + c) * VT_STR + row]) = u;
      }
    }
    __syncthreads();

    floatx4 st[4];
#pragma unroll
    for (int kf = 0; kf < 4; ++kf) {
      floatx4 c = (floatx4){0.f, 0.f, 0.f, 0.f};
#pragma unroll
      for (int kd = 0; kd < 4; ++kd) {
        short8 a = *(const short8*)(&Klds[(kf * 16 + l15) * KT_STR + kd * 32 + quad * 8]);
        c = __builtin_amdgcn_mfma_f32_16x16x32_bf16(a, bq[kd], c, 0, 0, 0);
      }
      st[kf] = c;
    }

    if (s == nsteps - 1) {
#pragma unroll
      for (int kf = 0; kf < 4; ++kf)
#pragma unroll
        for (int r = 0; r < 4; ++r) {
          int key = kt + kf * 16 + quad * 4 + r;
          if (key > qg) st[kf][r] = -1e30f;
        }
    }

    float mx = st[0][0];
#pragma unroll
    for (int kf = 0; kf < 4; ++kf)
#pragma unroll
      for (int r = 0; r < 4; ++r) mx = fmaxf(mx, st[kf][r]);
    mx = fmaxf(mx, __shfl_xor(mx, 16, 64));
    mx = fmaxf(mx, __shfl_xor(mx, 32, 64));
    const float m_new = fmaxf(m_run, mx);
    const float alpha = EXP2F((m_run - m_new) * CSC);

    float p[4][4];
    float tsum = 0.f;
#pragma unroll
    for (int kf = 0; kf < 4; ++kf)
#pragma unroll
      for (int r = 0; r < 4; ++r) {
        p[kf][r] = EXP2F((st[kf][r] - m_new) * CSC);
        tsum += p[kf][r];
      }
    tsum += __shfl_xor(tsum, 16, 64);
    tsum += __shfl_xor(tsum, 32, 64);
    l_run = l_run * alpha + tsum;
    m_run = m_new;

#pragma unroll
    for (int r = 0; r < 4; ++r) {
      const float ar = __shfl(alpha, quad * 4 + r, 64);
#pragma unroll
      for (int nc = 0; nc < 8; ++nc) acc[nc][r] *= ar;
    }

    short* pw = &Plds[(w * 16 + l15) * PT_STR];
#pragma unroll
    for (int kf = 0; kf < 4; ++kf) {
      uint2 u;
      u.x = bfpack2(p[kf][0], p[kf][1]);
      u.y = bfpack2(p[kf][2], p[kf][3]);
      *(uint2*)(&pw[kf * 16 + quad * 4]) = u;
    }
    __asm__ __volatile__("" ::: "memory");
    short8 pa0 = *(const short8*)(&pw[quad * 8]);
    short8 pa1 = *(const short8*)(&pw[32 + quad * 8]);

#pragma unroll
    for (int nc = 0; nc < 8; ++nc) {
      short8 bv0 = *(const short8*)(&Vtlds[(nc * 16 + l15) * VT_STR + quad * 8]);
      acc[nc] = __builtin_amdgcn_mfma_f32_16x16x32_bf16(pa0, bv0, acc[nc], 0, 0, 0);
      short8 bv1 = *(const short8*)(&Vtlds[(nc * 16 + l15) * VT_STR + 32 + quad * 8]);
      acc[nc] = __builtin_amdgcn_mfma_f32_16x16x32_bf16(pa1, bv1, acc[nc], 0, 0, 0);
    }
    __syncthreads();
  }

#pragma unroll
  for (int r = 0; r < 4; ++r) {
    const float lr  = __shfl(l_run, quad * 4 + r, 64);
    const float inv = 1.0f / lr;
    const int qout  = q0 + w * 16 + quad * 4 + r;
    float* op = O + (size_t)(b * S_LEN + qout) * D_K + l15;
#pragma unroll
    for (int nc = 0; nc < 8; ++nc) op[nc * 16] = acc[nc][r] * inv;
  }
}

// ======================= launch =======================

extern "C" void kernel_launch(void* const* d_in, const int* in_sizes, int n_in,
                              void* d_out, int out_size, void* d_ws, size_t ws_size,
                              hipStream_t stream) {
  const float* Q = (const float*)d_in[0];
  const float* K = (const float*)d_in[1];
  const float* V = (const float*)d_in[2];
  float* O = (float*)d_out;

  const size_t elems = (size_t)B_SZ * S_LEN * D_K;   // 4.19M

  // ws layout (bytes):
  //   0        : counter (int)
  //   256      : ml      [2048 slots][64 q][m,l]  = 1,048,576
  //   1,048,832: partO   [2048 slots][64][128]f32 = 67,108,864
  //   68,157,696: Kb bf16                          =  8,388,608
  //   76,546,304: Vt bf16                          =  8,388,608
  const size_t off_ml = 256;
  const size_t off_po = off_ml + 2048ull * 128 * 4;
  const size_t off_kb = off_po + 2048ull * 8192 * 4;
  const size_t off_vt = off_kb + elems * 2;
  const size_t need   = off_vt + elems * 2;

  if (ws_size >= need) {
    char* ws = (char*)d_ws;
    int*            cnt = (int*)ws;
    float*          ml  = (float*)(ws + off_ml);
    float*          po  = (float*)(ws + off_po);
    unsigned short* Kb  = (unsigned short*)(ws + off_kb);
    unsigned short* Vt  = (unsigned short*)(ws + off_vt);

    zero_cnt<<<dim3(1), dim3(1), 0, stream>>>(cnt);
    conv_k<<<dim3((unsigned)(elems / 8 / 256)), dim3(256), 0, stream>>>(K, Kb);
    transp_v<<<dim3(B_SZ * (S_LEN / 64) * (D_K / 64)), dim3(256), 0, stream>>>(V, Vt);
    attn_worker<<<dim3(1024), dim3(128), 0, stream>>>(Q, Kb, Vt, cnt, ml, po);
    attn_combine<<<dim3(512), dim3(256), 0, stream>>>(ml, po, O);
  } else {
    attn_fwd_fb<<<dim3(512), dim3(256), 0, stream>>>(Q, K, V, O);
  }
}